// Round 9
// baseline (60.856 us; speedup 1.0000x reference)
//
#include <hip/hip_runtime.h>
#include <math.h>

#define T_LEN   40000
#define BATCH   64
#define RESET_T 30000
#define SUB     8
// regime 1: steps 1..29999 -> 3750 sub-chunks of 8 (3749 full, last = 7)
// regime 2: steps 30000..39999 -> 1250 sub-chunks of 8 (all full)
#define NS1     3750
#define L1_LAST 7
#define NS2     1250
#define NS      (NS1 + NS2)
// scan groups: 8 subs each (64 steps); groups 0..467 full, group 468 = 6 subs (47 steps)
#define NG      469
#define NGFULL  468
#define NROUNDS 9
#define PI_D    3.14159265358979323846

// shared table in d_ws (doubles):
#define T_A8    0      // 7 mats: A^(8*(i+1)), i=0..6  (A8..A56)
#define T_M64   112    // 9 mats: (A^64)^(2^r), r=0..8
#define T_A7    256    // 1 mat
#define T_LAM   272    // 2 osc * 11 * (re,im) = 44
#define T_TOTAL 316

// d_out layout in FLOATS (complex outputs validated as real part only):
// y     : (B,T,2) re-only -> B*T*2 floats at 0
// b     : (1,T)           -> T floats
// a     : (1,T)           -> T floats
// y_sum : (B,T,1) re-only -> B*T floats
#define Y_SIZE  ((size_t)BATCH * T_LEN * 2)
#define B_OFF   (Y_SIZE)
#define A_OFF   (B_OFF + T_LEN)
#define YS_OFF  (A_OFF + T_LEN)

struct Params { double alpha, beta, g0, g1, delta, k; };

__device__ __forceinline__ Params make_params(double c, double th0, double th1,
                                              double a, double b) {
    double inva = 1.0 / (1.0 + a);
    double bb   = b / (1.0 + b);
    Params p;
    p.alpha = 1.0 + c * (inva - 1.0);
    p.beta  = 1.0 + c * (inva - 1.0 + bb);
    p.g0    = c * inva * th0;
    p.g1    = c * inva * th1;
    p.delta = c * bb;
    p.k     = c * bb;
    return p;
}

__device__ __forceinline__ void get_consts(const float* tau, const float* omega,
                                           double& c, double& th0, double& th1) {
    double tv = (double)tau[0];
    c   = 0.1 / tv;
    th0 = 2.0 * PI_D * tv * (double)omega[0];
    th1 = 2.0 * PI_D * tv * (double)omega[1];
}

__device__ __forceinline__ void step(const Params& P, double& R0, double& I0,
                                     double& R1, double& I1, double z0, double z1) {
    double nR0 = P.alpha * R0 - P.g0 * I0 - P.delta * R1 + P.k * z0;
    double nI0 = P.g0 * R0 + P.beta * I0;
    double nR1 = P.alpha * R1 - P.g1 * I1 - P.delta * R0 + P.k * z1;
    double nI1 = P.g1 * R1 + P.beta * I1;
    R0 = nR0; I0 = nI0; R1 = nR1; I1 = nI1;
}

__device__ __forceinline__ void matmul4(const double* A, const double* B, double* C) {
    for (int i = 0; i < 4; ++i)
        for (int jj = 0; jj < 4; ++jj) {
            double s = 0.0;
            for (int l = 0; l < 4; ++l) s += A[i * 4 + l] * B[l * 4 + jj];
            C[i * 4 + jj] = s;
        }
}

__device__ void build_A(const Params& P, double* A) {
    A[0]  = P.alpha; A[1]  = -P.g0;  A[2]  = -P.delta; A[3]  = 0.0;
    A[4]  = P.g0;    A[5]  = P.beta; A[6]  = 0.0;      A[7]  = 0.0;
    A[8]  = -P.delta;A[9]  = 0.0;    A[10] = P.alpha;  A[11] = -P.g1;
    A[12] = 0.0;     A[13] = 0.0;    A[14] = P.g1;     A[15] = P.beta;
}

// ---------------- K1: 8-step particular solutions + b/a fill + table build ----------------
// p_out layout [b][j]; table built by (block 0, thread 0) hidden under k1's bulk work.
__global__ __launch_bounds__(256) void k1_partial(const float* __restrict__ X,
        const float* tau, const float* omega, const float* a0, const float* b0,
        double* __restrict__ p_out, float* __restrict__ b_out, float* __restrict__ a_out,
        double* __restrict__ t_ws) {
    int tid = blockIdx.x * blockDim.x + threadIdx.x;
    if (tid < T_LEN) {
        b_out[tid] = (tid < RESET_T) ? b0[0] : 0.0f;
        a_out[tid] = (tid < RESET_T) ? a0[0] : 0.0f;
    }
    double c, th0, th1; get_consts(tau, omega, c, th0, th1);
    Params P = make_params(c, th0, th1, (double)a0[0], (double)b0[0]);

    if (tid == 0) {
        // build all uniform tables once for k2 (serial, hidden under other blocks)
        double A1[16], A2m[16], A4m[16], A6m[16];
        build_A(P, A1);
        matmul4(A1, A1, A2m);
        matmul4(A2m, A2m, A4m);
        matmul4(A4m, A4m, &t_ws[T_A8]);                    // A8
        for (int i = 1; i < 7; ++i)                        // A16..A56
            matmul4(&t_ws[T_A8 + (i-1)*16], &t_ws[T_A8], &t_ws[T_A8 + i*16]);
        matmul4(&t_ws[T_A8 + 6*16], &t_ws[T_A8], &t_ws[T_M64]);   // A64
        for (int r = 1; r < NROUNDS; ++r)
            matmul4(&t_ws[T_M64 + (r-1)*16], &t_ws[T_M64 + (r-1)*16],
                    &t_ws[T_M64 + r*16]);
        matmul4(A4m, A2m, A6m);
        matmul4(A6m, A1, &t_ws[T_A7]);                     // A7
        for (int o = 0; o < 2; ++o) {
            double ct = c * ((o == 0) ? th0 : th1);
            double lr = 1.0, li = ct;                      // lam^1
            for (int k = 0; k < 3; ++k) {                  // ^8
                double nr = lr*lr - li*li, ni = 2.0*lr*li; lr = nr; li = ni;
            }
            t_ws[T_LAM + (o*11 + 0)*2 + 0] = lr; t_ws[T_LAM + (o*11 + 0)*2 + 1] = li;
            for (int k = 1; k < 11; ++k) {
                double nr = lr*lr - li*li, ni = 2.0*lr*li; lr = nr; li = ni;
                t_ws[T_LAM + (o*11 + k)*2 + 0] = lr;
                t_ws[T_LAM + (o*11 + k)*2 + 1] = li;
            }
        }
    }

    if (tid >= BATCH * NS1) return;
    int j = tid % NS1, b = tid / NS1;
    int t0 = 1 + j * SUB;
    int len = (j < NS1 - 1) ? SUB : L1_LAST;
    double R0 = 0, I0 = 0, R1 = 0, I1 = 0;
    const float* xb = X + (size_t)b * T_LEN * 2 + (size_t)t0 * 2;
    if (len == SUB) {
        #pragma unroll
        for (int s = 0; s < SUB; ++s) {
            float2 z = *(const float2*)(xb + 2 * s);
            step(P, R0, I0, R1, I1, (double)z.x, (double)z.y);
        }
    } else {
        for (int s = 0; s < len; ++s) {
            float2 z = *(const float2*)(xb + 2 * s);
            step(P, R0, I0, R1, I1, (double)z.x, (double)z.y);
        }
    }
    double* out = p_out + ((size_t)b * NS1 + j) * 4;
    out[0] = R0; out[1] = I0; out[2] = R1; out[3] = I1;
}

// ---------------- K2: combine(8x8->64) + Kogge-Stone scan + expand(64->8) ----------------
__global__ __launch_bounds__(512) void k2_scan_par(const float* tau, const float* omega,
        const float* a0, const float* b0, const double* __restrict__ p_in,
        const double* __restrict__ t_ws,
        double* __restrict__ s_out, double* __restrict__ invn) {
    __shared__ double v[NGFULL * 5];      // stride 5: bank-conflict-free
    __shared__ double Tl[T_TOTAL];        // tables from k1
    __shared__ double send1[4];
    int b = blockIdx.x;
    int j = threadIdx.x;

    for (int i = j; i < T_TOTAL; i += 512) Tl[i] = t_ws[i];

    double c, th0, th1; get_consts(tau, omega, c, th0, th1);

    // load the 8 sub-partials of group j (kept in registers for expansion)
    double pk[8][4];
    int nsub = (j < NGFULL) ? 8 : (j == NGFULL ? 6 : 0);
    if (nsub) {
        const double* p = p_in + ((size_t)b * NS1 + 8*j) * 4;
        for (int k = 0; k < 8; ++k)
            if (k < nsub) { pk[k][0]=p[k*4]; pk[k][1]=p[k*4+1];
                            pk[k][2]=p[k*4+2]; pk[k][3]=p[k*4+3]; }
    }
    __syncthreads();

    // combine: pg = p7 + sum_{k=0..6} A^(8*(7-k)) * p_k
    if (j < NGFULL) {
        for (int i = 0; i < 4; ++i) {
            double s = pk[7][i];
            for (int k = 0; k < 7; ++k) {
                const double* M = &Tl[T_A8 + (6 - k) * 16];
                s += M[i*4+0]*pk[k][0] + M[i*4+1]*pk[k][1]
                   + M[i*4+2]*pk[k][2] + M[i*4+3]*pk[k][3];
            }
            v[j*5 + i] = s;
        }
    }
    __syncthreads();

    // inclusive Kogge-Stone over full groups 0..467
    for (int r = 0, d = 1; r < NROUNDS; ++r, d <<= 1) {
        const double* M = &Tl[T_M64 + r * 16];
        double n0 = 0, n1 = 0, n2 = 0, n3 = 0;
        bool act = (j < NGFULL) && (j >= d);
        if (act) {
            const double* q = &v[(j - d) * 5];
            double q0 = q[0], q1 = q[1], q2 = q[2], q3 = q[3];
            const double* w = &v[j * 5];
            n0 = M[0]  * q0 + M[1]  * q1 + M[2]  * q2 + M[3]  * q3 + w[0];
            n1 = M[4]  * q0 + M[5]  * q1 + M[6]  * q2 + M[7]  * q3 + w[1];
            n2 = M[8]  * q0 + M[9]  * q1 + M[10] * q2 + M[11] * q3 + w[2];
            n3 = M[12] * q0 + M[13] * q1 + M[14] * q2 + M[15] * q3 + w[3];
        }
        __syncthreads();
        if (act) { v[j*5+0] = n0; v[j*5+1] = n1; v[j*5+2] = n2; v[j*5+3] = n3; }
        __syncthreads();
    }

    // expand: group start -> 8-granularity sub starts (s = A8*s + p_k)
    if (j <= NGFULL) {
        const double* A8m = &Tl[T_A8];
        double s[4] = {0, 0, 0, 0};
        if (j > 0) { s[0]=v[(j-1)*5+0]; s[1]=v[(j-1)*5+1];
                     s[2]=v[(j-1)*5+2]; s[3]=v[(j-1)*5+3]; }
        int sub0 = 8 * j;
        for (int k = 0; k < nsub; ++k) {
            double* so = s_out + ((size_t)b * NS + (sub0 + k)) * 4;
            so[0]=s[0]; so[1]=s[1]; so[2]=s[2]; so[3]=s[3];
            if (k < nsub - 1) {
                double ns[4];
                for (int i = 0; i < 4; ++i)
                    ns[i] = A8m[i*4+0]*s[0] + A8m[i*4+1]*s[1]
                          + A8m[i*4+2]*s[2] + A8m[i*4+3]*s[3] + pk[k][i];
                s[0]=ns[0]; s[1]=ns[1]; s[2]=ns[2]; s[3]=ns[3];
            }
        }
        if (j == NGFULL) {
            // s = start of sub 3749 (7-step); s_end1 = A7*s + p(3749)
            const double* A7m = &Tl[T_A7];
            double e[4];
            for (int i = 0; i < 4; ++i)
                e[i] = A7m[i*4+0]*s[0] + A7m[i*4+1]*s[1]
                     + A7m[i*4+2]*s[2] + A7m[i*4+3]*s[3] + pk[5][i];
            send1[0]=e[0]; send1[1]=e[1]; send1[2]=e[2]; send1[3]=e[3];
            if (b == 0) {
                double ct0 = c * th0;   // y[0,RESET_T,0] = (1 + j*c*th0)*(e0 + j*e1)
                double yr = e[0] - ct0 * e[1];
                double yi = ct0 * e[0] + e[1];
                invn[0] = 1.0 / sqrt(yr * yr + yi * yi);
            }
        }
    }
    __syncthreads();

    // regime-2 sub starts: lam^(8m) * s_end1, m = 0..1249
    for (int m = j; m < NS2; m += 512) {
        double q0r = 1.0, q0i = 0.0, q1r = 1.0, q1i = 0.0;
        for (int k = 0; k < 11; ++k) {
            if (m & (1 << k)) {
                double l0r = Tl[T_LAM + (0*11+k)*2+0], l0i = Tl[T_LAM + (0*11+k)*2+1];
                double l1r = Tl[T_LAM + (1*11+k)*2+0], l1i = Tl[T_LAM + (1*11+k)*2+1];
                double t0r = q0r*l0r - q0i*l0i, t0i = q0r*l0i + q0i*l0r;
                double t1r = q1r*l1r - q1i*l1i, t1i = q1r*l1i + q1i*l1r;
                q0r=t0r; q0i=t0i; q1r=t1r; q1i=t1i;
            }
        }
        double e0 = send1[0], e1 = send1[1], e2 = send1[2], e3 = send1[3];
        double* so = s_out + ((size_t)b * NS + (NS1 + m)) * 4;
        so[0] = q0r * e0 - q0i * e1;
        so[1] = q0i * e0 + q0r * e1;
        so[2] = q1r * e2 - q1i * e3;
        so[3] = q1i * e2 + q1r * e3;
    }
}

// ---------------- K3: 8-step replay, write NORMALIZED Re(y) + fused y_sum ----------------
__global__ __launch_bounds__(256) void k3_replay(const float* __restrict__ X,
        const float* tau, const float* omega, const float* a0, const float* b0,
        const double* __restrict__ s_in, const double* __restrict__ invn,
        float* __restrict__ y_out, float* __restrict__ ysum_out) {
    int tid = blockIdx.x * blockDim.x + threadIdx.x;
    if (tid >= BATCH * NS) return;
    int j = tid % NS, b = tid / NS;
    double c, th0, th1; get_consts(tau, omega, c, th0, th1);
    const double* sp = s_in + ((size_t)b * NS + j) * 4;
    double R0 = sp[0], I0 = sp[1], R1 = sp[2], I1 = sp[3];
    double inv = invn[0];
    float* yb = y_out + (size_t)b * T_LEN * 2;
    float* sb = ysum_out + (size_t)b * T_LEN;
    if (j == 0) {
        *(float2*)yb = make_float2(0.f, 0.f);  // y[:,0,:] = 0
        sb[0] = 0.f;                           // ysum[0] = 0
        sb[1] = 0.f;                           // ysum[1] = sum(y[0]) = 0
    }
    if (j < NS1) {
        Params P = make_params(c, th0, th1, (double)a0[0], (double)b0[0]);
        int t0 = 1 + j * SUB;
        int len = (j < NS1 - 1) ? SUB : L1_LAST;
        const float* xb = X + (size_t)b * T_LEN * 2 + (size_t)t0 * 2;
        if (len == SUB) {
            #pragma unroll
            for (int s = 0; s < SUB; ++s) {
                int t = t0 + s;
                float2 z = *(const float2*)(xb + 2 * s);
                step(P, R0, I0, R1, I1, (double)z.x, (double)z.y);
                *(float2*)(yb + (size_t)t * 2) =
                    make_float2((float)(R0 * inv), (float)(R1 * inv));
                sb[t + 1] = (float)((R0 + R1) * inv);
            }
        } else {
            for (int s = 0; s < len; ++s) {
                int t = t0 + s;
                float2 z = *(const float2*)(xb + 2 * s);
                step(P, R0, I0, R1, I1, (double)z.x, (double)z.y);
                *(float2*)(yb + (size_t)t * 2) =
                    make_float2((float)(R0 * inv), (float)(R1 * inv));
                sb[t + 1] = (float)((R0 + R1) * inv);
            }
        }
    } else {
        Params P = make_params(c, th0, th1, 0.0, 0.0);
        int m = j - NS1;
        int t0 = RESET_T + m * SUB;
        #pragma unroll
        for (int s = 0; s < SUB; ++s) {
            int t = t0 + s;
            step(P, R0, I0, R1, I1, 0.0, 0.0);
            *(float2*)(yb + (size_t)t * 2) =
                make_float2((float)(R0 * inv), (float)(R1 * inv));
            if (t + 1 < T_LEN) sb[t + 1] = (float)((R0 + R1) * inv);
        }
    }
}

extern "C" void kernel_launch(void* const* d_in, const int* in_sizes, int n_in,
                              void* d_out, int out_size, void* d_ws, size_t ws_size,
                              hipStream_t stream) {
    const float* X     = (const float*)d_in[0];
    const float* tau   = (const float*)d_in[1];
    const float* omega = (const float*)d_in[2];
    const float* a0    = (const float*)d_in[3];
    const float* b0    = (const float*)d_in[4];
    float* out = (float*)d_out;

    // Scratch in d_ws (~18 MB of 256 MiB); fully rewritten every call.
    double* p_ws = (double*)d_ws;                        // [BATCH][NS1][4]
    double* s_ws = p_ws + (size_t)NS1 * BATCH * 4;       // [BATCH][NS][4]
    double* invn = s_ws + (size_t)NS * BATCH * 4;
    double* t_ws = invn + 8;                             // T_TOTAL doubles

    int n1 = BATCH * NS1;   // 240,000 (also covers T_LEN=40,000 b/a fill)
    k1_partial<<<(n1 + 255) / 256, 256, 0, stream>>>(X, tau, omega, a0, b0, p_ws,
                                                     out + B_OFF, out + A_OFF, t_ws);
    k2_scan_par<<<BATCH, 512, 0, stream>>>(tau, omega, a0, b0, p_ws, t_ws, s_ws, invn);
    int n3 = BATCH * NS;    // 320,000
    k3_replay<<<(n3 + 255) / 256, 256, 0, stream>>>(X, tau, omega, a0, b0, s_ws, invn,
                                                    out, out + YS_OFF);
}

// Round 10
// 45.924 us; speedup vs baseline: 1.3252x; 1.3252x over previous
//
#include <hip/hip_runtime.h>
#include <math.h>

#define T_LEN   40000
#define BATCH   64
#define RESET_T 30000
#define SUB     16
// regime 1: steps 1..29999 -> 1875 sub-chunks of 16 (1874 full, last = 15)
// regime 2: steps 30000..39999 -> 625 sub-chunks of 16 (all full)
#define NS1     1875
#define L1_LAST 15
#define NS2     625
#define NS      (NS1 + NS2)
// scan groups: 4 subs each (64 steps); groups 0..467 full, group 468 = 3 subs (47 steps)
#define NG      469
#define NGFULL  468
#define NROUNDS 9
#define PI_D    3.14159265358979323846

// uniform table in d_ws (doubles):
#define T_A16   0      // 3 mats: A^16, A^32, A^48
#define T_M64   48     // 9 mats: (A^64)^(2^r), r=0..8
#define T_A15   192    // 1 mat: A^15
#define T_LAM   208    // 2 osc * 10 * (re,im) = 40
#define T_TOTAL 248

// d_out layout in FLOATS (complex outputs validated as real part only):
// y     : (B,T,2) re-only -> B*T*2 floats at 0
// b     : (1,T)           -> T floats
// a     : (1,T)           -> T floats
// y_sum : (B,T,1) re-only -> B*T floats
#define Y_SIZE  ((size_t)BATCH * T_LEN * 2)
#define B_OFF   (Y_SIZE)
#define A_OFF   (B_OFF + T_LEN)
#define YS_OFF  (A_OFF + T_LEN)

struct Params { double alpha, beta, g0, g1, delta, k; };

__device__ __forceinline__ Params make_params(double c, double th0, double th1,
                                              double a, double b) {
    double inva = 1.0 / (1.0 + a);
    double bb   = b / (1.0 + b);
    Params p;
    p.alpha = 1.0 + c * (inva - 1.0);
    p.beta  = 1.0 + c * (inva - 1.0 + bb);
    p.g0    = c * inva * th0;
    p.g1    = c * inva * th1;
    p.delta = c * bb;
    p.k     = c * bb;
    return p;
}

__device__ __forceinline__ void get_consts(const float* tau, const float* omega,
                                           double& c, double& th0, double& th1) {
    double tv = (double)tau[0];
    c   = 0.1 / tv;
    th0 = 2.0 * PI_D * tv * (double)omega[0];
    th1 = 2.0 * PI_D * tv * (double)omega[1];
}

__device__ __forceinline__ void step(const Params& P, double& R0, double& I0,
                                     double& R1, double& I1, double z0, double z1) {
    double nR0 = P.alpha * R0 - P.g0 * I0 - P.delta * R1 + P.k * z0;
    double nI0 = P.g0 * R0 + P.beta * I0;
    double nR1 = P.alpha * R1 - P.g1 * I1 - P.delta * R0 + P.k * z1;
    double nI1 = P.g1 * R1 + P.beta * I1;
    R0 = nR0; I0 = nI0; R1 = nR1; I1 = nI1;
}

__device__ __forceinline__ void matmul4(const double* A, const double* B, double* C) {
    for (int i = 0; i < 4; ++i)
        for (int jj = 0; jj < 4; ++jj) {
            double s = 0.0;
            for (int l = 0; l < 4; ++l) s += A[i * 4 + l] * B[l * 4 + jj];
            C[i * 4 + jj] = s;
        }
}

__device__ void build_A(const Params& P, double* A) {
    A[0]  = P.alpha; A[1]  = -P.g0;  A[2]  = -P.delta; A[3]  = 0.0;
    A[4]  = P.g0;    A[5]  = P.beta; A[6]  = 0.0;      A[7]  = 0.0;
    A[8]  = -P.delta;A[9]  = 0.0;    A[10] = P.alpha;  A[11] = -P.g1;
    A[12] = 0.0;     A[13] = 0.0;    A[14] = P.g1;     A[15] = P.beta;
}

// ---------------- K1: 16-step particular solutions + b/a fill + table build ----------------
// p_out layout [b][j] (coalesced); tables built by thread 0, hidden under bulk work.
__global__ __launch_bounds__(256) void k1_partial(const float* __restrict__ X,
        const float* tau, const float* omega, const float* a0, const float* b0,
        double* __restrict__ p_out, float* __restrict__ b_out, float* __restrict__ a_out,
        double* __restrict__ t_ws) {
    int tid = blockIdx.x * blockDim.x + threadIdx.x;
    if (tid < T_LEN) {
        b_out[tid] = (tid < RESET_T) ? b0[0] : 0.0f;
        a_out[tid] = (tid < RESET_T) ? a0[0] : 0.0f;
    }
    double c, th0, th1; get_consts(tau, omega, c, th0, th1);
    Params P = make_params(c, th0, th1, (double)a0[0], (double)b0[0]);

    if (tid == 0) {
        double A1[16], A2m[16], A4m[16], A8m[16], t14[16];
        build_A(P, A1);
        matmul4(A1, A1, A2m);
        matmul4(A2m, A2m, A4m);
        matmul4(A4m, A4m, A8m);
        matmul4(A8m, A8m, &t_ws[T_A16]);                       // A16
        matmul4(&t_ws[T_A16], &t_ws[T_A16], &t_ws[T_A16+16]);  // A32
        matmul4(&t_ws[T_A16+16], &t_ws[T_A16], &t_ws[T_A16+32]); // A48
        matmul4(&t_ws[T_A16+32], &t_ws[T_A16], &t_ws[T_M64]);  // A64
        for (int r = 1; r < NROUNDS; ++r)
            matmul4(&t_ws[T_M64 + (r-1)*16], &t_ws[T_M64 + (r-1)*16],
                    &t_ws[T_M64 + r*16]);
        matmul4(A8m, A4m, t14); matmul4(t14, A2m, &t_ws[T_A15]); // A14, then A15? no:
        // A15 = A8*A4*A2*A1
        matmul4(&t_ws[T_A15], A1, t14);                        // (A14)*A1 = A15
        for (int i = 0; i < 16; ++i) t_ws[T_A15 + i] = t14[i];
        for (int o = 0; o < 2; ++o) {
            double ct = c * ((o == 0) ? th0 : th1);
            double lr = 1.0, li = ct;                          // lam^1
            for (int k = 0; k < 4; ++k) {                      // ^16
                double nr = lr*lr - li*li, ni = 2.0*lr*li; lr = nr; li = ni;
            }
            t_ws[T_LAM + (o*10 + 0)*2 + 0] = lr; t_ws[T_LAM + (o*10 + 0)*2 + 1] = li;
            for (int k = 1; k < 10; ++k) {
                double nr = lr*lr - li*li, ni = 2.0*lr*li; lr = nr; li = ni;
                t_ws[T_LAM + (o*10 + k)*2 + 0] = lr;
                t_ws[T_LAM + (o*10 + k)*2 + 1] = li;
            }
        }
    }

    if (tid >= BATCH * NS1) return;
    int j = tid % NS1, b = tid / NS1;
    int t0 = 1 + j * SUB;
    int len = (j < NS1 - 1) ? SUB : L1_LAST;
    double R0 = 0, I0 = 0, R1 = 0, I1 = 0;
    const float* xb = X + (size_t)b * T_LEN * 2 + (size_t)t0 * 2;
    if (len == SUB) {
        #pragma unroll
        for (int s = 0; s < SUB; ++s) {
            float2 z = *(const float2*)(xb + 2 * s);
            step(P, R0, I0, R1, I1, (double)z.x, (double)z.y);
        }
    } else {
        for (int s = 0; s < len; ++s) {
            float2 z = *(const float2*)(xb + 2 * s);
            step(P, R0, I0, R1, I1, (double)z.x, (double)z.y);
        }
    }
    double* out = p_out + ((size_t)b * NS1 + j) * 4;
    out[0] = R0; out[1] = I0; out[2] = R1; out[3] = I1;
}

// ---------------- K2: combine(4x16->64) + Kogge-Stone + expand(64->16) ----------------
// All register arrays use compile-time indices only (no scratch spill).
__global__ __launch_bounds__(512) void k2_scan_par(const float* tau, const float* omega,
        const float* a0, const float* b0, const double* __restrict__ p_in,
        const double* __restrict__ t_ws,
        double* __restrict__ s_out, double* __restrict__ invn) {
    __shared__ double v[NGFULL * 5];      // stride 5: bank-conflict-free
    __shared__ double Tl[T_TOTAL];        // tables from k1
    __shared__ double send1[4];
    int b = blockIdx.x;
    int j = threadIdx.x;

    for (int i = j; i < T_TOTAL; i += 512) Tl[i] = t_ws[i];

    double c, th0, th1; get_consts(tau, omega, c, th0, th1);

    // load the 4 sub-partials of group j into NAMED registers
    double p00=0,p01=0,p02=0,p03=0, p10=0,p11=0,p12=0,p13=0;
    double p20=0,p21=0,p22=0,p23=0, p30=0,p31=0,p32=0,p33=0;
    if (j < NGFULL) {
        const double* p = p_in + ((size_t)b * NS1 + 4*j) * 4;
        p00=p[0];  p01=p[1];  p02=p[2];  p03=p[3];
        p10=p[4];  p11=p[5];  p12=p[6];  p13=p[7];
        p20=p[8];  p21=p[9];  p22=p[10]; p23=p[11];
        p30=p[12]; p31=p[13]; p32=p[14]; p33=p[15];
    } else if (j == NGFULL) {  // subs 1872..1874
        const double* p = p_in + ((size_t)b * NS1 + 4*j) * 4;
        p00=p[0];  p01=p[1];  p02=p[2];  p03=p[3];
        p10=p[4];  p11=p[5];  p12=p[6];  p13=p[7];
        p20=p[8];  p21=p[9];  p22=p[10]; p23=p[11];
    }
    __syncthreads();

    // combine: pg = A48 p0 + A32 p1 + A16 p2 + p3
    if (j < NGFULL) {
        const double* M48 = &Tl[T_A16 + 32];
        const double* M32 = &Tl[T_A16 + 16];
        const double* M16 = &Tl[T_A16];
        #pragma unroll
        for (int i = 0; i < 4; ++i) {
            double s = (i==0?p30:i==1?p31:i==2?p32:p33);
            s += M48[i*4+0]*p00 + M48[i*4+1]*p01 + M48[i*4+2]*p02 + M48[i*4+3]*p03;
            s += M32[i*4+0]*p10 + M32[i*4+1]*p11 + M32[i*4+2]*p12 + M32[i*4+3]*p13;
            s += M16[i*4+0]*p20 + M16[i*4+1]*p21 + M16[i*4+2]*p22 + M16[i*4+3]*p23;
            v[j*5 + i] = s;
        }
    }
    __syncthreads();

    // inclusive Kogge-Stone over full groups 0..467
    for (int r = 0, d = 1; r < NROUNDS; ++r, d <<= 1) {
        const double* M = &Tl[T_M64 + r * 16];
        double n0 = 0, n1 = 0, n2 = 0, n3 = 0;
        bool act = (j < NGFULL) && (j >= d);
        if (act) {
            const double* q = &v[(j - d) * 5];
            double q0 = q[0], q1 = q[1], q2 = q[2], q3 = q[3];
            const double* w = &v[j * 5];
            n0 = M[0]  * q0 + M[1]  * q1 + M[2]  * q2 + M[3]  * q3 + w[0];
            n1 = M[4]  * q0 + M[5]  * q1 + M[6]  * q2 + M[7]  * q3 + w[1];
            n2 = M[8]  * q0 + M[9]  * q1 + M[10] * q2 + M[11] * q3 + w[2];
            n3 = M[12] * q0 + M[13] * q1 + M[14] * q2 + M[15] * q3 + w[3];
        }
        __syncthreads();
        if (act) { v[j*5+0] = n0; v[j*5+1] = n1; v[j*5+2] = n2; v[j*5+3] = n3; }
        __syncthreads();
    }

    // expand: group start -> 16-granularity sub starts, fully unrolled
    if (j <= NGFULL) {
        const double* A16m = &Tl[T_A16];
        double s0 = 0, s1 = 0, s2 = 0, s3 = 0;
        if (j > 0) { s0=v[(j-1)*5+0]; s1=v[(j-1)*5+1]; s2=v[(j-1)*5+2]; s3=v[(j-1)*5+3]; }
        double* so = s_out + ((size_t)b * NS + 4*j) * 4;
        #define STORE4(off) { so[(off)*4+0]=s0; so[(off)*4+1]=s1; so[(off)*4+2]=s2; so[(off)*4+3]=s3; }
        #define ADV(q0,q1,q2,q3) { \
            double a_ = A16m[0]*s0 + A16m[1]*s1 + A16m[2]*s2 + A16m[3]*s3 + q0; \
            double b_ = A16m[4]*s0 + A16m[5]*s1 + A16m[6]*s2 + A16m[7]*s3 + q1; \
            double c_ = A16m[8]*s0 + A16m[9]*s1 + A16m[10]*s2 + A16m[11]*s3 + q2; \
            double d_ = A16m[12]*s0 + A16m[13]*s1 + A16m[14]*s2 + A16m[15]*s3 + q3; \
            s0=a_; s1=b_; s2=c_; s3=d_; }
        if (j < NGFULL) {
            STORE4(0);
            ADV(p00,p01,p02,p03); STORE4(1);
            ADV(p10,p11,p12,p13); STORE4(2);
            ADV(p20,p21,p22,p23); STORE4(3);
        } else {
            STORE4(0);
            ADV(p00,p01,p02,p03); STORE4(1);
            ADV(p10,p11,p12,p13); STORE4(2);
            // s_end1 = A15 * start(sub 1874) + p2
            const double* A15m = &Tl[T_A15];
            double e0 = A15m[0]*s0 + A15m[1]*s1 + A15m[2]*s2 + A15m[3]*s3 + p20;
            double e1 = A15m[4]*s0 + A15m[5]*s1 + A15m[6]*s2 + A15m[7]*s3 + p21;
            double e2 = A15m[8]*s0 + A15m[9]*s1 + A15m[10]*s2 + A15m[11]*s3 + p22;
            double e3 = A15m[12]*s0 + A15m[13]*s1 + A15m[14]*s2 + A15m[15]*s3 + p23;
            send1[0]=e0; send1[1]=e1; send1[2]=e2; send1[3]=e3;
            if (b == 0) {
                double ct0 = c * th0;   // y[0,RESET_T,0] = (1 + j*c*th0)*(e0 + j*e1)
                double yr = e0 - ct0 * e1;
                double yi = ct0 * e0 + e1;
                invn[0] = 1.0 / sqrt(yr * yr + yi * yi);
            }
        }
        #undef STORE4
        #undef ADV
    }
    __syncthreads();

    // regime-2 sub starts: lam^(16m) * s_end1, m = 0..624
    for (int m = j; m < NS2; m += 512) {
        double q0r = 1.0, q0i = 0.0, q1r = 1.0, q1i = 0.0;
        #pragma unroll
        for (int k = 0; k < 10; ++k) {
            if (m & (1 << k)) {
                double l0r = Tl[T_LAM + (0*10+k)*2+0], l0i = Tl[T_LAM + (0*10+k)*2+1];
                double l1r = Tl[T_LAM + (1*10+k)*2+0], l1i = Tl[T_LAM + (1*10+k)*2+1];
                double t0r = q0r*l0r - q0i*l0i, t0i = q0r*l0i + q0i*l0r;
                double t1r = q1r*l1r - q1i*l1i, t1i = q1r*l1i + q1i*l1r;
                q0r=t0r; q0i=t0i; q1r=t1r; q1i=t1i;
            }
        }
        double e0 = send1[0], e1 = send1[1], e2 = send1[2], e3 = send1[3];
        double* so = s_out + ((size_t)b * NS + (NS1 + m)) * 4;
        so[0] = q0r * e0 - q0i * e1;
        so[1] = q0i * e0 + q0r * e1;
        so[2] = q1r * e2 - q1i * e3;
        so[3] = q1i * e2 + q1r * e3;
    }
}

// ---------------- K3: 16-step replay, write NORMALIZED Re(y) + fused y_sum ----------------
__global__ __launch_bounds__(256) void k3_replay(const float* __restrict__ X,
        const float* tau, const float* omega, const float* a0, const float* b0,
        const double* __restrict__ s_in, const double* __restrict__ invn,
        float* __restrict__ y_out, float* __restrict__ ysum_out) {
    int tid = blockIdx.x * blockDim.x + threadIdx.x;
    if (tid >= BATCH * NS) return;
    int j = tid % NS, b = tid / NS;
    double c, th0, th1; get_consts(tau, omega, c, th0, th1);
    const double* sp = s_in + ((size_t)b * NS + j) * 4;
    double R0 = sp[0], I0 = sp[1], R1 = sp[2], I1 = sp[3];
    double inv = invn[0];
    float* yb = y_out + (size_t)b * T_LEN * 2;
    float* sb = ysum_out + (size_t)b * T_LEN;
    if (j == 0) {
        *(float2*)yb = make_float2(0.f, 0.f);  // y[:,0,:] = 0
        sb[0] = 0.f;                           // ysum[0] = 0
        sb[1] = 0.f;                           // ysum[1] = sum(y[0]) = 0
    }
    if (j < NS1) {
        Params P = make_params(c, th0, th1, (double)a0[0], (double)b0[0]);
        int t0 = 1 + j * SUB;
        int len = (j < NS1 - 1) ? SUB : L1_LAST;
        const float* xb = X + (size_t)b * T_LEN * 2 + (size_t)t0 * 2;
        if (len == SUB) {
            #pragma unroll
            for (int s = 0; s < SUB; ++s) {
                int t = t0 + s;
                float2 z = *(const float2*)(xb + 2 * s);
                step(P, R0, I0, R1, I1, (double)z.x, (double)z.y);
                *(float2*)(yb + (size_t)t * 2) =
                    make_float2((float)(R0 * inv), (float)(R1 * inv));
                sb[t + 1] = (float)((R0 + R1) * inv);
            }
        } else {
            for (int s = 0; s < len; ++s) {
                int t = t0 + s;
                float2 z = *(const float2*)(xb + 2 * s);
                step(P, R0, I0, R1, I1, (double)z.x, (double)z.y);
                *(float2*)(yb + (size_t)t * 2) =
                    make_float2((float)(R0 * inv), (float)(R1 * inv));
                sb[t + 1] = (float)((R0 + R1) * inv);
            }
        }
    } else {
        Params P = make_params(c, th0, th1, 0.0, 0.0);
        int m = j - NS1;
        int t0 = RESET_T + m * SUB;
        #pragma unroll
        for (int s = 0; s < SUB; ++s) {
            int t = t0 + s;
            step(P, R0, I0, R1, I1, 0.0, 0.0);
            *(float2*)(yb + (size_t)t * 2) =
                make_float2((float)(R0 * inv), (float)(R1 * inv));
            if (t + 1 < T_LEN) sb[t + 1] = (float)((R0 + R1) * inv);
        }
    }
}

extern "C" void kernel_launch(void* const* d_in, const int* in_sizes, int n_in,
                              void* d_out, int out_size, void* d_ws, size_t ws_size,
                              hipStream_t stream) {
    const float* X     = (const float*)d_in[0];
    const float* tau   = (const float*)d_in[1];
    const float* omega = (const float*)d_in[2];
    const float* a0    = (const float*)d_in[3];
    const float* b0    = (const float*)d_in[4];
    float* out = (float*)d_out;

    // Scratch in d_ws (~9 MB of 256 MiB); fully rewritten every call.
    double* p_ws = (double*)d_ws;                        // [BATCH][NS1][4]
    double* s_ws = p_ws + (size_t)NS1 * BATCH * 4;       // [BATCH][NS][4]
    double* invn = s_ws + (size_t)NS * BATCH * 4;
    double* t_ws = invn + 8;                             // T_TOTAL doubles

    int n1 = BATCH * NS1;   // 120,000 (also covers T_LEN=40,000 b/a fill)
    k1_partial<<<(n1 + 255) / 256, 256, 0, stream>>>(X, tau, omega, a0, b0, p_ws,
                                                     out + B_OFF, out + A_OFF, t_ws);
    k2_scan_par<<<BATCH, 512, 0, stream>>>(tau, omega, a0, b0, p_ws, t_ws, s_ws, invn);
    int n3 = BATCH * NS;    // 160,000
    k3_replay<<<(n3 + 255) / 256, 256, 0, stream>>>(X, tau, omega, a0, b0, s_ws, invn,
                                                    out, out + YS_OFF);
}